// Round 3
// baseline (3771.083 us; speedup 1.0000x reference)
//
#include <hip/hip_runtime.h>
#include <stdint.h>
#include <math.h>

#define T_SEQ 2048
#define DIM   1024
#define NLAY  12
#define NH    16
#define DHH   64
#define FF    3584
#define CHUNK 32
#define NCH   64

typedef __bf16 bf16;
typedef __attribute__((ext_vector_type(8))) __bf16 bf16x8;
typedef __attribute__((ext_vector_type(4))) __bf16 bf16x4;
typedef __attribute__((ext_vector_type(4))) float f32x4;

#define AS1 __attribute__((address_space(1)))
#define AS3 __attribute__((address_space(3)))

__device__ __forceinline__ void async_cp16(const bf16* g, bf16* l) {
  __builtin_amdgcn_global_load_lds((AS1 void*)(uintptr_t)g, (AS3 void*)l, 16, 0, 0);
}

__device__ __forceinline__ float siluf(float x) { return x / (1.f + expf(-x)); }

// block-wide (256 thr) sum of 4 values, result broadcast to all threads
__device__ __forceinline__ void block_reduce_4(float& a, float& b, float& c, float& d) {
#pragma unroll
  for (int off = 32; off >= 1; off >>= 1) {
    a += __shfl_xor(a, off, 64);
    b += __shfl_xor(b, off, 64);
    c += __shfl_xor(c, off, 64);
    d += __shfl_xor(d, off, 64);
  }
  __shared__ float red[4][4];
  int wid = threadIdx.x >> 6;
  if ((threadIdx.x & 63) == 0) { red[wid][0] = a; red[wid][1] = b; red[wid][2] = c; red[wid][3] = d; }
  __syncthreads();
  a = red[0][0] + red[1][0] + red[2][0] + red[3][0];
  b = red[0][1] + red[1][1] + red[2][1] + red[3][1];
  c = red[0][2] + red[1][2] + red[2][2] + red[3][2];
  d = red[0][3] + red[1][3] + red[2][3] + red[3][3];
}

// ---------------- embedding + ln0 ----------------
__global__ __launch_bounds__(256) void k_embed(const int* __restrict__ idx,
                                               const float* __restrict__ emb,
                                               const float* __restrict__ w,
                                               const float* __restrict__ b,
                                               float* __restrict__ x) {
  int t = blockIdx.x, tid = threadIdx.x, c = tid * 4;
  long row = idx[t];
  float4 xc = *(const float4*)&emb[row * DIM + c];
  float s = xc.x + xc.y + xc.z + xc.w;
  float q = xc.x * xc.x + xc.y * xc.y + xc.z * xc.z + xc.w * xc.w;
  float d2 = 0.f, d3 = 0.f;
  block_reduce_4(s, q, d2, d3);
  float m = s * (1.f / DIM), var = q * (1.f / DIM) - m * m;
  float rs = rsqrtf(var + 1e-5f);
  float4 lw = *(const float4*)&w[c], lb = *(const float4*)&b[c];
  float4 o;
  o.x = (xc.x - m) * rs * lw.x + lb.x;
  o.y = (xc.y - m) * rs * lw.y + lb.y;
  o.z = (xc.z - m) * rs * lw.z + lb.z;
  o.w = (xc.w - m) * rs * lw.w + lb.w;
  *(float4*)&x[(long)t * DIM + c] = o;
}

// ---------------- layernorm + token-shift mix ----------------
__global__ __launch_bounds__(256) void k_lnmix(const float* __restrict__ x,
                                               const float* __restrict__ lnw,
                                               const float* __restrict__ lnb,
                                               const float* __restrict__ mx0,
                                               const float* __restrict__ mx1,
                                               const float* __restrict__ mx2,
                                               const float* __restrict__ mx3,
                                               bf16* __restrict__ out, int nmix) {
  int t = blockIdx.x, tid = threadIdx.x, c = tid * 4;
  float4 xc = *(const float4*)&x[(long)t * DIM + c];
  float4 xp = {0.f, 0.f, 0.f, 0.f};
  if (t > 0) xp = *(const float4*)&x[(long)(t - 1) * DIM + c];
  float s1 = xc.x + xc.y + xc.z + xc.w;
  float q1 = xc.x * xc.x + xc.y * xc.y + xc.z * xc.z + xc.w * xc.w;
  float s2 = xp.x + xp.y + xp.z + xp.w;
  float q2 = xp.x * xp.x + xp.y * xp.y + xp.z * xp.z + xp.w * xp.w;
  block_reduce_4(s1, q1, s2, q2);
  float m1 = s1 * (1.f / DIM), v1 = q1 * (1.f / DIM) - m1 * m1, rs1 = rsqrtf(v1 + 1e-5f);
  float m2 = s2 * (1.f / DIM), v2 = q2 * (1.f / DIM) - m2 * m2, rs2 = rsqrtf(v2 + 1e-5f);
  float4 lw = *(const float4*)&lnw[c], lb = *(const float4*)&lnb[c];
  float xs[4] = {xc.x, xc.y, xc.z, xc.w}, xps[4] = {xp.x, xp.y, xp.z, xp.w};
  float lws[4] = {lw.x, lw.y, lw.z, lw.w}, lbs[4] = {lb.x, lb.y, lb.z, lb.w};
  float xn[4], sx[4];
#pragma unroll
  for (int j = 0; j < 4; j++) {
    xn[j] = (xs[j] - m1) * rs1 * lws[j] + lbs[j];
    sx[j] = (t > 0) ? ((xps[j] - m2) * rs2 * lws[j] + lbs[j]) : 0.f;
  }
  for (int mi = 0; mi < nmix; mi++) {
    const float* mp = (mi == 0) ? mx0 : (mi == 1) ? mx1 : (mi == 2) ? mx2 : mx3;
    float4 mv = *(const float4*)&mp[c];
    float ms[4] = {mv.x, mv.y, mv.z, mv.w};
    bf16x4 o;
#pragma unroll
    for (int j = 0; j < 4; j++) o[j] = (bf16)(xn[j] * ms[j] + sx[j] * (1.f - ms[j]));
    *(bf16x4*)&out[(long)mi * T_SEQ * DIM + (long)t * DIM + c] = o;
  }
}

// ---------------- weight transpose+cast fp32 KxN -> bf16 NxK ----------------
struct TrArgs {
  const float* src[8];
  bf16* dst[8];
  int K[8];
  int N[8];
  int tstart[9];
};

__global__ __launch_bounds__(256) void k_trans(TrArgs a) {
  int bid = blockIdx.x;
  int m = 0;
#pragma unroll
  for (int i = 1; i < 8; i++)
    if (bid >= a.tstart[i]) m = i;
  int tl = bid - a.tstart[m];
  int N = a.N[m], K = a.K[m];
  int ntN = N >> 6;
  int tn = tl % ntN, tk = tl / ntN;
  const float* src = a.src[m];
  bf16* dst = a.dst[m];
  __shared__ __align__(16) float tile[64][65];
  int tid = threadIdx.x;
  int r = tid >> 2, cq = (tid & 3) * 16;
  const float* sp = &src[(long)(tk * 64 + r) * N + tn * 64 + cq];
#pragma unroll
  for (int j = 0; j < 16; j += 4) {
    float4 v = *(const float4*)&sp[j];
    tile[r][cq + j] = v.x;
    tile[r][cq + j + 1] = v.y;
    tile[r][cq + j + 2] = v.z;
    tile[r][cq + j + 3] = v.w;
  }
  __syncthreads();
  int rn = tid >> 2, kq = (tid & 3) * 16;
  bf16* dp = &dst[(long)(tn * 64 + rn) * K + tk * 64 + kq];
#pragma unroll
  for (int h = 0; h < 2; h++) {
    bf16x8 o8;
#pragma unroll
    for (int j = 0; j < 8; j++) o8[j] = (bf16)tile[kq + h * 8 + j][rn];
    *(bf16x8*)&dp[h * 8] = o8;
  }
}

// ---------------- bf16 MFMA GEMM, 2-phase double-buffered LDS ----------------
// Tiles: 128 x BN x 32 (BN = 128 or 64).
// MODE 0: out bf16 (z==3 -> silu)   1: relu^2 -> bf16   2: sigmoid -> f32
//      3: f32 out += acc (residual) 4: f32 out += AUX*acc
#define BMT 128
#define BKT 32

template <int MODE, int BN>
__global__ __launch_bounds__(256) void k_gemm(const bf16* __restrict__ A,
                                              const bf16* __restrict__ Bt,
                                              void* __restrict__ OUTv,
                                              const float* __restrict__ AUX,
                                              int M, int N, int K,
                                              long zsA, long zsB, long zsO) {
  constexpr int NJ = BN / 32;  // 16-wide j-fragments per wave
  __shared__ __align__(16) bf16 sA[2][BMT * BKT];
  __shared__ __align__(16) bf16 sB[2][BN * BKT];
  int z = blockIdx.z;
  A += (long)z * zsA;
  Bt += (long)z * zsB;
  long zo = (long)z * zsO;
  int n0 = blockIdx.x * BN, m0 = blockIdx.y * BMT;
  int tid = threadIdx.x, lane = tid & 63, wid = tid >> 6;
  int wm = (wid >> 1) * 64, wn = (wid & 1) * (BN / 2);

  f32x4 acc[4][NJ];
#pragma unroll
  for (int i = 0; i < 4; i++)
#pragma unroll
    for (int j = 0; j < NJ; j++) {
      f32x4 zv = {0.f, 0.f, 0.f, 0.f};
      acc[i][j] = zv;
    }

  int r0 = tid >> 2, c0 = (tid & 3) * 8;
  const bf16* gA0 = A + (long)(m0 + r0) * K + c0;
  const bf16* gA1 = A + (long)(m0 + r0 + 64) * K + c0;
  const bf16* gB0 = Bt + (long)(n0 + r0) * K + c0;
  const bf16* gB1 = Bt + (long)(n0 + r0 + 64) * K + c0;  // only used when BN==128

  int kq = (lane >> 4) * 8;
  int fm = lane & 15;

#define STAGE(buf, kk)                                        \
  {                                                           \
    async_cp16(gA0 + (kk), &sA[buf][wid * 512]);              \
    async_cp16(gA1 + (kk), &sA[buf][wid * 512 + 2048]);       \
    async_cp16(gB0 + (kk), &sB[buf][wid * 512]);              \
    if constexpr (BN == 128)                                  \
      async_cp16(gB1 + (kk), &sB[buf][wid * 512 + 2048]);     \
  }

  int nst = K / BKT;
  STAGE(0, 0);
  __syncthreads();  // drains vmcnt(0): buffer 0 resident

  int cur = 0;
  for (int t = 0; t < nst; ++t) {
    if (t + 1 < nst) STAGE(cur ^ 1, (t + 1) * BKT);  // prefetch next tile (in flight during MFMA)
    bf16x8 af[4], bfr[NJ];
#pragma unroll
    for (int i = 0; i < 4; i++)
      af[i] = *(const bf16x8*)&sA[cur][(wm + i * 16 + fm) * BKT + kq];
#pragma unroll
    for (int j = 0; j < NJ; j++)
      bfr[j] = *(const bf16x8*)&sB[cur][(wn + j * 16 + fm) * BKT + kq];
#pragma unroll
    for (int i = 0; i < 4; i++)
#pragma unroll
      for (int j = 0; j < NJ; j++)
        acc[i][j] = __builtin_amdgcn_mfma_f32_16x16x32_bf16(af[i], bfr[j], acc[i][j], 0, 0, 0);
    __syncthreads();  // per-wave vmcnt(0) drain (cheap: loads had whole phase) + reuse fence
    cur ^= 1;
  }
#undef STAGE

  int col0 = n0 + wn + (lane & 15);
  int row0 = m0 + wm + ((lane >> 4) << 2);
  bf16* Ob = (bf16*)OUTv + zo;
  float* Of = (float*)OUTv + zo;
  bool dosilu = (z == 3);
#pragma unroll
  for (int i = 0; i < 4; i++)
#pragma unroll
    for (int j = 0; j < NJ; j++)
#pragma unroll
      for (int r = 0; r < 4; r++) {
        int row = row0 + i * 16 + r;
        int col = col0 + j * 16;
        long idx = (long)row * N + col;
        float v = acc[i][j][r];
        if constexpr (MODE == 0) {
          if (dosilu) v = siluf(v);
          Ob[idx] = (bf16)v;
        } else if constexpr (MODE == 1) {
          v = fmaxf(v, 0.f);
          Ob[idx] = (bf16)(v * v);
        } else if constexpr (MODE == 2) {
          Of[idx] = 1.f / (1.f + expf(-v));
        } else if constexpr (MODE == 3) {
          Of[idx] += v;
        } else {
          Of[idx] += AUX[idx] * v;
        }
      }
}

// ---------------- WKV phase A: per-chunk state delta ----------------
__global__ __launch_bounds__(256) void k_wkva(const bf16* __restrict__ kmat,
                                              const bf16* __restrict__ vmat,
                                              const float* __restrict__ decay_l,
                                              float* __restrict__ dS) {
  int c = blockIdx.x, h = blockIdx.y, tid = threadIdx.x;
  __shared__ __align__(16) float kh[CHUNK][DHH];
  __shared__ __align__(16) float vl[CHUNK][DHH];
  int s = tid >> 3, d0 = (tid & 7) * 8;
  float p = (float)(CHUNK - 1 - s);
  long base = (long)(c * CHUNK + s) * DIM + h * DHH + d0;
  bf16x8 k8 = *(const bf16x8*)&kmat[base];
  bf16x8 v8 = *(const bf16x8*)&vmat[base];
#pragma unroll
  for (int j = 0; j < 8; j++) {
    float e2 = expf(decay_l[h * DHH + d0 + j]) * 1.4426950408889634f;
    kh[s][d0 + j] = (float)k8[j] * exp2f(-p * e2);
    vl[s][d0 + j] = (float)v8[j];
  }
  __syncthreads();
  int d = tid >> 2, e0 = (tid & 3) * 16;
  float acc[16];
#pragma unroll
  for (int j = 0; j < 16; j++) acc[j] = 0.f;
  for (int ss = 0; ss < CHUNK; ss++) {
    float kc = kh[ss][d];
#pragma unroll
    for (int j = 0; j < 16; j += 4) {
      float4 vv = *(const float4*)&vl[ss][e0 + j];
      acc[j] = fmaf(kc, vv.x, acc[j]);
      acc[j + 1] = fmaf(kc, vv.y, acc[j + 1]);
      acc[j + 2] = fmaf(kc, vv.z, acc[j + 2]);
      acc[j + 3] = fmaf(kc, vv.w, acc[j + 3]);
    }
  }
  float* out = &dS[(((long)c * NH + h) * DHH + d) * DHH + e0];
#pragma unroll
  for (int j = 0; j < 16; j += 4) {
    float4 o = {acc[j], acc[j + 1], acc[j + 2], acc[j + 3]};
    *(float4*)&out[j] = o;
  }
}

// ---------------- WKV phase B: sequential chunk-level scan (in place) ----------------
__global__ __launch_bounds__(256) void k_wkvb(float* __restrict__ dS,
                                              const float* __restrict__ decay_l) {
  int id = blockIdx.x * 256 + threadIdx.x;  // < NH*DHH*DHH
  int h = id >> 12, d = (id >> 6) & 63;
  float e2 = expf(decay_l[h * DHH + d]);
  float wc = expf(-(float)CHUNK * e2);
  float S = 0.f;
  for (int c = 0; c < NCH; c++) {
    float* p = &dS[(long)c * (NH * DHH * DHH) + id];
    float v = *p;
    *p = S;           // state at chunk start
    S = wc * S + v;   // advance
  }
}

// ---------------- WKV phase C: in-chunk replay + groupnorm + gate ----------------
#define WKV_STEP(dd, rc, kc, uc, oa)          \
  {                                           \
    float kv_ = (kc)*ve;                      \
    float tmp_ = fmaf((uc), ve, S[dd]);       \
    oa = fmaf((rc), tmp_, oa);                \
    S[dd] = fmaf(w[dd], S[dd], kv_);          \
  }

__global__ __launch_bounds__(64, 1) void k_wkvc(const bf16* __restrict__ rmat,
                                                const bf16* __restrict__ kmat,
                                                const bf16* __restrict__ vmat,
                                                const bf16* __restrict__ gmat,
                                                const float* __restrict__ decay_l,
                                                const float* __restrict__ faaaa_l,
                                                const float* __restrict__ lnxw,
                                                const float* __restrict__ lnxb,
                                                const float* __restrict__ Sc,
                                                bf16* __restrict__ y) {
  int c = blockIdx.x, h = blockIdx.y, lane = threadIdx.x;
  __shared__ __align__(16) float rl[CHUNK][DHH];
  __shared__ __align__(16) float kl[CHUNK][DHH];
  __shared__ __align__(16) float ukl[CHUNK][DHH];
  __shared__ __align__(16) float vls[CHUNK][DHH];
  __shared__ __align__(16) float wl[DHH];
  float u = faaaa_l[h * DHH + lane];
  wl[lane] = expf(-expf(decay_l[h * DHH + lane]));
  for (int i = 0; i < CHUNK; i++) {
    long base = (long)(c * CHUNK + i) * DIM + h * DHH + lane;
    float rv = (float)rmat[base], kv = (float)kmat[base], vv = (float)vmat[base];
    rl[i][lane] = rv;
    kl[i][lane] = kv;
    ukl[i][lane] = u * kv;
    vls[i][lane] = vv;
  }
  __syncthreads();
  float w[64], S[64];
#pragma unroll
  for (int q = 0; q < 16; q++) {
    float4 t4 = *(const float4*)&wl[q * 4];
    w[q * 4] = t4.x;
    w[q * 4 + 1] = t4.y;
    w[q * 4 + 2] = t4.z;
    w[q * 4 + 3] = t4.w;
  }
  const float* Sp = &Sc[((long)c * NH + h) * DHH * DHH + lane];
#pragma unroll
  for (int d = 0; d < 64; d++) S[d] = Sp[(long)d * DHH];
  float lw = lnxw[h * DHH + lane], lb = lnxb[h * DHH + lane];
#pragma unroll 1
  for (int t = 0; t < CHUNK; t++) {
    float ve = vls[t][lane];
    float o0 = 0.f, o1 = 0.f;
#pragma unroll
    for (int q = 0; q < 16; q++) {
      float4 r4 = *(const float4*)&rl[t][q * 4];
      float4 k4 = *(const float4*)&kl[t][q * 4];
      float4 u4 = *(const float4*)&ukl[t][q * 4];
      WKV_STEP(q * 4 + 0, r4.x, k4.x, u4.x, o0);
      WKV_STEP(q * 4 + 1, r4.y, k4.y, u4.y, o1);
      WKV_STEP(q * 4 + 2, r4.z, k4.z, u4.z, o0);
      WKV_STEP(q * 4 + 3, r4.w, k4.w, u4.w, o1);
    }
    float o = o0 + o1;
    float s1 = o, s2 = o * o;
#pragma unroll
    for (int off = 32; off >= 1; off >>= 1) {
      s1 += __shfl_xor(s1, off, 64);
      s2 += __shfl_xor(s2, off, 64);
    }
    float m = s1 * (1.f / 64.f), var = s2 * (1.f / 64.f) - m * m;
    float gn = (o - m) * rsqrtf(var + 1e-5f) * lw + lb;
    long gi = (long)(c * CHUNK + t) * DIM + h * DHH + lane;
    float gv = (float)gmat[gi];  // silu already applied by GEMM epilogue
    y[gi] = (bf16)(gn * gv);
  }
}

// ---------------- final LN + classifier on last token ----------------
__global__ __launch_bounds__(256) void k_final(const float* __restrict__ x,
                                               const float* __restrict__ w,
                                               const float* __restrict__ b,
                                               const float* __restrict__ sw,
                                               float* __restrict__ out) {
  int tid = threadIdx.x, c = tid * 4;
  float4 xc = *(const float4*)&x[(long)(T_SEQ - 1) * DIM + c];
  float s = xc.x + xc.y + xc.z + xc.w;
  float q = xc.x * xc.x + xc.y * xc.y + xc.z * xc.z + xc.w * xc.w;
  float d2 = 0.f, d3 = 0.f;
  block_reduce_4(s, q, d2, d3);
  float m = s * (1.f / DIM), var = q * (1.f / DIM) - m * m;
  float rs = rsqrtf(var + 1e-5f);
  float xs[4] = {xc.x, xc.y, xc.z, xc.w};
  float p0 = 0.f, p1 = 0.f;
#pragma unroll
  for (int j = 0; j < 4; j++) {
    float xn = (xs[j] - m) * rs * w[c + j] + b[c + j];
    p0 += xn * sw[c + j];
    p1 += xn * sw[DIM + c + j];
  }
  float e0 = 0.f, e1 = 0.f;
  block_reduce_4(p0, p1, e0, e1);
  if (tid == 0) {
    out[0] = p0;
    out[1] = p1;
  }
}

// ---------------- launcher ----------------
extern "C" void kernel_launch(void* const* d_in, const int* in_sizes, int n_in,
                              void* d_out, int out_size, void* d_ws, size_t ws_size,
                              hipStream_t stream) {
  (void)in_sizes; (void)n_in; (void)out_size; (void)ws_size;
  const int* idx = (const int*)d_in[0];
  const float* emb = (const float*)d_in[1];
  const float* ln0w = (const float*)d_in[2];
  const float* ln0b = (const float*)d_in[3];
  const float* ln1w = (const float*)d_in[4];
  const float* ln1b = (const float*)d_in[5];
  const float* mixr = (const float*)d_in[6];
  const float* mixk = (const float*)d_in[7];
  const float* mixv = (const float*)d_in[8];
  const float* mixg = (const float*)d_in[9];
  const float* decay = (const float*)d_in[10];
  const float* faaaa = (const float*)d_in[11];
  const float* Wr = (const float*)d_in[12];
  const float* Wk = (const float*)d_in[13];
  const float* Wv = (const float*)d_in[14];
  const float* Wg = (const float*)d_in[15];
  const float* Wo = (const float*)d_in[16];
  const float* lnxw = (const float*)d_in[17];
  const float* lnxb = (const float*)d_in[18];
  const float* ln2w = (const float*)d_in[19];
  const float* ln2b = (const float*)d_in[20];
  const float* cmixk = (const float*)d_in[21];
  const float* cmixr = (const float*)d_in[22];
  const float* cWk = (const float*)d_in[23];
  const float* cWv = (const float*)d_in[24];
  const float* cWr = (const float*)d_in[25];
  const float* lnoutw = (const float*)d_in[26];
  const float* lnoutb = (const float*)d_in[27];
  const float* scorew = (const float*)d_in[28];

  uint8_t* w8 = (uint8_t*)d_ws;
  float* xbuf = (float*)(w8 + 0);            //  8 MB fp32 T*D
  bf16* mix4 = (bf16*)(w8 + 8388608);        // 16 MB: xr|xk|xv|xg (bf16 T*D each)
  bf16* rkvg = (bf16*)(w8 + 25165824);       // 16 MB: r|k|v|g
  bf16* ybuf = (bf16*)(w8 + 41943040);       //  4 MB
  float* rrbuf = (float*)(w8 + 46137344);    //  8 MB
  bf16* kkbuf = (bf16*)(w8 + 54525952);      // 14 MB (T*F)
  float* dS = (float*)(w8 + 69206016);       // 16 MB (NCH*NH*DH*DH)
  bf16* Wt = (bf16*)(w8 + 85983232);         // 26 MB transposed layer weights

  const long TD = (long)T_SEQ * DIM;
  const long DD = (long)DIM * DIM;
  const long DF = (long)DIM * FF;

  bf16* WrT = Wt;              // r,k,v,g at stride DD
  bf16* WoT = Wt + 4 * DD;
  bf16* cWkT = Wt + 5 * DD;    // FF x DIM
  bf16* cWvT = cWkT + DF;      // DIM x FF
  bf16* cWrT = cWvT + DF;      // DIM x DIM

  k_embed<<<T_SEQ, 256, 0, stream>>>(idx, emb, ln0w, ln0b, xbuf);

  for (int l = 0; l < NLAY; l++) {
    TrArgs ta;
    ta.src[0] = Wr + (long)l * DD;  ta.dst[0] = Wt + 0 * DD; ta.K[0] = DIM; ta.N[0] = DIM;
    ta.src[1] = Wk + (long)l * DD;  ta.dst[1] = Wt + 1 * DD; ta.K[1] = DIM; ta.N[1] = DIM;
    ta.src[2] = Wv + (long)l * DD;  ta.dst[2] = Wt + 2 * DD; ta.K[2] = DIM; ta.N[2] = DIM;
    ta.src[3] = Wg + (long)l * DD;  ta.dst[3] = Wt + 3 * DD; ta.K[3] = DIM; ta.N[3] = DIM;
    ta.src[4] = Wo + (long)l * DD;  ta.dst[4] = WoT;         ta.K[4] = DIM; ta.N[4] = DIM;
    ta.src[5] = cWk + (long)l * DF; ta.dst[5] = cWkT;        ta.K[5] = DIM; ta.N[5] = FF;
    ta.src[6] = cWv + (long)l * DF; ta.dst[6] = cWvT;        ta.K[6] = FF;  ta.N[6] = DIM;
    ta.src[7] = cWr + (long)l * DD; ta.dst[7] = cWrT;        ta.K[7] = DIM; ta.N[7] = DIM;
    const int ts[9] = {0, 256, 512, 768, 1024, 1280, 2176, 3072, 3328};
    for (int i = 0; i < 9; i++) ta.tstart[i] = ts[i];
    k_trans<<<3328, 256, 0, stream>>>(ta);

    k_lnmix<<<T_SEQ, 256, 0, stream>>>(xbuf, ln1w + l * DIM, ln1b + l * DIM,
                                       mixr + l * DIM, mixk + l * DIM,
                                       mixv + l * DIM, mixg + l * DIM, mix4, 4);

    // r|k|v|g: z=4 batch, 512 blocks -> BN=128
    k_gemm<0, 128><<<dim3(8, 16, 4), 256, 0, stream>>>(mix4, WrT, (void*)rkvg, nullptr,
                                                       T_SEQ, DIM, DIM, TD, DD, TD);

    k_wkva<<<dim3(NCH, NH), 256, 0, stream>>>(rkvg + TD, rkvg + 2 * TD,
                                              decay + (long)l * NH * DHH, dS);
    k_wkvb<<<256, 256, 0, stream>>>(dS, decay + (long)l * NH * DHH);
    k_wkvc<<<dim3(NCH, NH), 64, 0, stream>>>(rkvg, rkvg + TD, rkvg + 2 * TD, rkvg + 3 * TD,
                                             decay + (long)l * NH * DHH,
                                             faaaa + (long)l * NH * DHH,
                                             lnxw + l * DIM, lnxb + l * DIM, dS, ybuf);

    // Wo residual: N=1024 single-z -> BN=64 for 256 blocks (full machine)
    k_gemm<3, 64><<<dim3(16, 16, 1), 256, 0, stream>>>(ybuf, WoT, (void*)xbuf, nullptr,
                                                       T_SEQ, DIM, DIM, 0, 0, 0);

    k_lnmix<<<T_SEQ, 256, 0, stream>>>(xbuf, ln2w + l * DIM, ln2b + l * DIM,
                                       cmixk + l * DIM, cmixr + l * DIM,
                                       nullptr, nullptr, mix4, 2);

    // cWk: N=3584, 448 blocks -> BN=128
    k_gemm<1, 128><<<dim3(28, 16, 1), 256, 0, stream>>>(mix4, cWkT, (void*)kkbuf, nullptr,
                                                        T_SEQ, FF, DIM, 0, 0, 0);
    // cWr sigmoid: N=1024 -> BN=64
    k_gemm<2, 64><<<dim3(16, 16, 1), 256, 0, stream>>>(mix4 + TD, cWrT, (void*)rrbuf, nullptr,
                                                       T_SEQ, DIM, DIM, 0, 0, 0);
    // cWv: N=1024, K=3584 -> BN=64
    k_gemm<4, 64><<<dim3(16, 16, 1), 256, 0, stream>>>(kkbuf, cWvT, (void*)xbuf, rrbuf,
                                                       T_SEQ, DIM, FF, 0, 0, 0);
  }

  k_final<<<1, 256, 0, stream>>>(xbuf, lnoutw, lnoutb, scorew, (float*)d_out);
}

// Round 5
// 3367.073 us; speedup vs baseline: 1.1200x; 1.1200x over previous
//
#include <hip/hip_runtime.h>
#include <stdint.h>
#include <math.h>

#define T_SEQ 2048
#define DIM   1024
#define NLAY  12
#define NH    16
#define DHH   64
#define FF    3584
#define CHUNK 32
#define NCH   64

typedef __bf16 bf16;
typedef __attribute__((ext_vector_type(8))) __bf16 bf16x8;
typedef __attribute__((ext_vector_type(4))) __bf16 bf16x4;
typedef __attribute__((ext_vector_type(4))) float f32x4;

#define AS1 __attribute__((address_space(1)))
#define AS3 __attribute__((address_space(3)))

__device__ __forceinline__ void async_cp16(const bf16* g, bf16* l) {
  __builtin_amdgcn_global_load_lds((AS1 void*)(uintptr_t)g, (AS3 void*)l, 16, 0, 0);
}

__device__ __forceinline__ float siluf(float x) { return x / (1.f + expf(-x)); }

// block-wide (256 thr) sum of 4 values, result broadcast to all threads
__device__ __forceinline__ void block_reduce_4(float& a, float& b, float& c, float& d) {
#pragma unroll
  for (int off = 32; off >= 1; off >>= 1) {
    a += __shfl_xor(a, off, 64);
    b += __shfl_xor(b, off, 64);
    c += __shfl_xor(c, off, 64);
    d += __shfl_xor(d, off, 64);
  }
  __shared__ float red[4][4];
  int wid = threadIdx.x >> 6;
  if ((threadIdx.x & 63) == 0) { red[wid][0] = a; red[wid][1] = b; red[wid][2] = c; red[wid][3] = d; }
  __syncthreads();
  a = red[0][0] + red[1][0] + red[2][0] + red[3][0];
  b = red[0][1] + red[1][1] + red[2][1] + red[3][1];
  c = red[0][2] + red[1][2] + red[2][2] + red[3][2];
  d = red[0][3] + red[1][3] + red[2][3] + red[3][3];
}

// ---------------- embedding + ln0 ----------------
__global__ __launch_bounds__(256) void k_embed(const int* __restrict__ idx,
                                               const float* __restrict__ emb,
                                               const float* __restrict__ w,
                                               const float* __restrict__ b,
                                               float* __restrict__ x) {
  int t = blockIdx.x, tid = threadIdx.x, c = tid * 4;
  long row = idx[t];
  float4 xc = *(const float4*)&emb[row * DIM + c];
  float s = xc.x + xc.y + xc.z + xc.w;
  float q = xc.x * xc.x + xc.y * xc.y + xc.z * xc.z + xc.w * xc.w;
  float d2 = 0.f, d3 = 0.f;
  block_reduce_4(s, q, d2, d3);
  float m = s * (1.f / DIM), var = q * (1.f / DIM) - m * m;
  float rs = rsqrtf(var + 1e-5f);
  float4 lw = *(const float4*)&w[c], lb = *(const float4*)&b[c];
  float4 o;
  o.x = (xc.x - m) * rs * lw.x + lb.x;
  o.y = (xc.y - m) * rs * lw.y + lb.y;
  o.z = (xc.z - m) * rs * lw.z + lb.z;
  o.w = (xc.w - m) * rs * lw.w + lb.w;
  *(float4*)&x[(long)t * DIM + c] = o;
}

// ---------------- layernorm + token-shift mix ----------------
__global__ __launch_bounds__(256) void k_lnmix(const float* __restrict__ x,
                                               const float* __restrict__ lnw,
                                               const float* __restrict__ lnb,
                                               const float* __restrict__ mx0,
                                               const float* __restrict__ mx1,
                                               const float* __restrict__ mx2,
                                               const float* __restrict__ mx3,
                                               bf16* __restrict__ out, int nmix) {
  int t = blockIdx.x, tid = threadIdx.x, c = tid * 4;
  float4 xc = *(const float4*)&x[(long)t * DIM + c];
  float4 xp = {0.f, 0.f, 0.f, 0.f};
  if (t > 0) xp = *(const float4*)&x[(long)(t - 1) * DIM + c];
  float s1 = xc.x + xc.y + xc.z + xc.w;
  float q1 = xc.x * xc.x + xc.y * xc.y + xc.z * xc.z + xc.w * xc.w;
  float s2 = xp.x + xp.y + xp.z + xp.w;
  float q2 = xp.x * xp.x + xp.y * xp.y + xp.z * xp.z + xp.w * xp.w;
  block_reduce_4(s1, q1, s2, q2);
  float m1 = s1 * (1.f / DIM), v1 = q1 * (1.f / DIM) - m1 * m1, rs1 = rsqrtf(v1 + 1e-5f);
  float m2 = s2 * (1.f / DIM), v2 = q2 * (1.f / DIM) - m2 * m2, rs2 = rsqrtf(v2 + 1e-5f);
  float4 lw = *(const float4*)&lnw[c], lb = *(const float4*)&lnb[c];
  float xs[4] = {xc.x, xc.y, xc.z, xc.w}, xps[4] = {xp.x, xp.y, xp.z, xp.w};
  float lws[4] = {lw.x, lw.y, lw.z, lw.w}, lbs[4] = {lb.x, lb.y, lb.z, lb.w};
  float xn[4], sx[4];
#pragma unroll
  for (int j = 0; j < 4; j++) {
    xn[j] = (xs[j] - m1) * rs1 * lws[j] + lbs[j];
    sx[j] = (t > 0) ? ((xps[j] - m2) * rs2 * lws[j] + lbs[j]) : 0.f;
  }
  for (int mi = 0; mi < nmix; mi++) {
    const float* mp = (mi == 0) ? mx0 : (mi == 1) ? mx1 : (mi == 2) ? mx2 : mx3;
    float4 mv = *(const float4*)&mp[c];
    float ms[4] = {mv.x, mv.y, mv.z, mv.w};
    bf16x4 o;
#pragma unroll
    for (int j = 0; j < 4; j++) o[j] = (bf16)(xn[j] * ms[j] + sx[j] * (1.f - ms[j]));
    *(bf16x4*)&out[(long)mi * T_SEQ * DIM + (long)t * DIM + c] = o;
  }
}

// ---------------- weight transpose+cast fp32 KxN -> bf16 NxK ----------------
struct TrArgs {
  const float* src[8];
  bf16* dst[8];
  int K[8];
  int N[8];
  int tstart[9];
};

__global__ __launch_bounds__(256) void k_trans(TrArgs a) {
  int bid = blockIdx.x;
  int m = 0;
#pragma unroll
  for (int i = 1; i < 8; i++)
    if (bid >= a.tstart[i]) m = i;
  int tl = bid - a.tstart[m];
  int N = a.N[m], K = a.K[m];
  int ntN = N >> 6;
  int tn = tl % ntN, tk = tl / ntN;
  const float* src = a.src[m];
  bf16* dst = a.dst[m];
  __shared__ __align__(16) float tile[64][65];
  int tid = threadIdx.x;
  int r = tid >> 2, cq = (tid & 3) * 16;
  const float* sp = &src[(long)(tk * 64 + r) * N + tn * 64 + cq];
#pragma unroll
  for (int j = 0; j < 16; j += 4) {
    float4 v = *(const float4*)&sp[j];
    tile[r][cq + j] = v.x;
    tile[r][cq + j + 1] = v.y;
    tile[r][cq + j + 2] = v.z;
    tile[r][cq + j + 3] = v.w;
  }
  __syncthreads();
  int rn = tid >> 2, kq = (tid & 3) * 16;
  bf16* dp = &dst[(long)(tn * 64 + rn) * K + tk * 64 + kq];
#pragma unroll
  for (int h = 0; h < 2; h++) {
    bf16x8 o8;
#pragma unroll
    for (int j = 0; j < 8; j++) o8[j] = (bf16)tile[kq + h * 8 + j][rn];
    *(bf16x8*)&dp[h * 8] = o8;
  }
}

// ---------------- bf16 MFMA GEMM ----------------
// 2-phase double-buffered LDS, BK=64, T2 XOR-swizzle (pre-swizzled global
// source + swizzled ds_read; LDS dest stays linear for global_load_lds).
// Tiles: 128 x BN x 64 (BN = 128 or 64). KS = split-K factor (blockIdx.z).
// MODE 0: out bf16, z-batched (z==3 -> silu)
//      3: f32 out atomic+= acc (residual)   [KS>1]
//      4: f32 out atomic+= AUX*acc          [KS>1]
//      5: fused cWk|cWr: n0<FF -> relu^2 bf16 OUT (A=mix4/xk2),
//                        n0>=FF -> sigmoid f32 AUX (A=mix4+zsA/xr2)
#define BMT 128
#define BKT 64

template <int MODE, int BN, int KS>
__global__ __launch_bounds__(256) void k_gemm(const bf16* __restrict__ A,
                                              const bf16* __restrict__ Bt,
                                              void* __restrict__ OUTv,
                                              const float* __restrict__ AUX,
                                              int M, int N, int K,
                                              long zsA, long zsB, long zsO) {
  constexpr int NJ = BN / 32;   // 16-wide j-fragments per wave
  constexpr int NRB = BN / 32;  // B staging rounds (32 rows each)
  __shared__ __align__(16) bf16 sA[2][BMT * BKT];
  __shared__ __align__(16) bf16 sB[2][BN * BKT];
  int z = blockIdx.z;
  long zo = 0;
  long koff = 0;
  int Klocal = K;
  int n0 = blockIdx.x * BN, m0 = blockIdx.y * BMT;
  if constexpr (MODE == 0) {
    A += (long)z * zsA;
    Bt += (long)z * zsB;
    zo = (long)z * zsO;
  } else if constexpr (MODE == 5) {
    if (n0 >= FF) A += zsA;  // cWr half reads xr2
  } else if constexpr (KS > 1) {
    Klocal = K / KS;
    koff = (long)z * Klocal;
  }
  int tid = threadIdx.x, lane = tid & 63, wid = tid >> 6;
  int wm = (wid >> 1) * 64, wn = (wid & 1) * (BN / 2);

  f32x4 acc[4][NJ];
#pragma unroll
  for (int i = 0; i < 4; i++)
#pragma unroll
    for (int j = 0; j < NJ; j++) {
      f32x4 zv = {0.f, 0.f, 0.f, 0.f};
      acc[i][j] = zv;
    }

  // staging: 256 thr x 16B = 32 rows x 128B per round; source col pre-swizzled
  // so linear LDS write + XOR'd ds_read yields correct fragments (rule #21).
  int r0 = tid >> 3;                              // 0..31
  int c0 = ((tid & 7) ^ ((tid >> 3) & 7)) * 8;    // swizzled element col
  const bf16* gA0 = A + (long)(m0 + r0) * K + koff + c0;
  const bf16* gB0 = Bt + (long)(n0 + r0) * K + koff + c0;
  int ldso = wid * 512;  // wave-uniform LDS base (elems); lane adds 16B

#define STAGE(buf, kk)                                                          \
  {                                                                             \
    _Pragma("unroll")                                                           \
    for (int rnd = 0; rnd < 4; rnd++)                                           \
      async_cp16(gA0 + (long)rnd * 32 * K + (kk), &sA[buf][ldso + rnd * 2048]); \
    _Pragma("unroll")                                                           \
    for (int rnd = 0; rnd < NRB; rnd++)                                         \
      async_cp16(gB0 + (long)rnd * 32 * K + (kk), &sB[buf][ldso + rnd * 2048]); \
  }

  int kq = (lane >> 4) * 8;
  int fm = lane & 15;
  int nst = Klocal / BKT;
  STAGE(0, 0);
  __syncthreads();  // drains vmcnt(0): buffer 0 resident

  int cur = 0;
  for (int t = 0; t < nst; ++t) {
    if (t + 1 < nst) STAGE(cur ^ 1, (t + 1) * BKT);  // prefetch overlaps MFMA
#pragma unroll
    for (int kk2 = 0; kk2 < 2; kk2++) {
      bf16x8 af[4], bfr[NJ];
#pragma unroll
      for (int i = 0; i < 4; i++) {
        int row = wm + i * 16 + fm;
        af[i] = *(const bf16x8*)&sA[cur][row * BKT + ((kk2 * 32 + kq) ^ ((row & 7) << 3))];
      }
#pragma unroll
      for (int j = 0; j < NJ; j++) {
        int row = wn + j * 16 + fm;
        bfr[j] = *(const bf16x8*)&sB[cur][row * BKT + ((kk2 * 32 + kq) ^ ((row & 7) << 3))];
      }
#pragma unroll
      for (int i = 0; i < 4; i++)
#pragma unroll
        for (int j = 0; j < NJ; j++)
          acc[i][j] = __builtin_amdgcn_mfma_f32_16x16x32_bf16(af[i], bfr[j], acc[i][j], 0, 0, 0);
    }
    __syncthreads();  // drain own loads (in flight the whole phase) + reuse fence
    cur ^= 1;
  }
#undef STAGE

  int col0 = n0 + wn + (lane & 15);
  int row0 = m0 + wm + ((lane >> 4) << 2);
  bf16* Ob = (bf16*)OUTv + zo;
  float* Of = (float*)OUTv + zo;
  bool dosilu = (z == 3);
#pragma unroll
  for (int i = 0; i < 4; i++)
#pragma unroll
    for (int j = 0; j < NJ; j++)
#pragma unroll
      for (int r = 0; r < 4; r++) {
        int row = row0 + i * 16 + r;
        int col = col0 + j * 16;
        long idx = (long)row * N + col;
        float v = acc[i][j][r];
        if constexpr (MODE == 0) {
          if (dosilu) v = siluf(v);
          Ob[idx] = (bf16)v;
        } else if constexpr (MODE == 3) {
          if constexpr (KS > 1) unsafeAtomicAdd(&Of[idx], v);
          else Of[idx] += v;
        } else if constexpr (MODE == 4) {
          if constexpr (KS > 1) unsafeAtomicAdd(&Of[idx], AUX[idx] * v);
          else Of[idx] += AUX[idx] * v;
        } else {  // MODE 5
          if (n0 < FF) {
            float vr = fmaxf(v, 0.f);
            ((bf16*)OUTv)[(long)row * FF + col] = (bf16)(vr * vr);
          } else {
            ((float*)AUX)[(long)row * DIM + (col - FF)] = 1.f / (1.f + expf(-v));
          }
        }
      }
}

// ---------------- WKV phase A: per-chunk state delta ----------------
__global__ __launch_bounds__(256) void k_wkva(const bf16* __restrict__ kmat,
                                              const bf16* __restrict__ vmat,
                                              const float* __restrict__ decay_l,
                                              float* __restrict__ dS) {
  int c = blockIdx.x, h = blockIdx.y, tid = threadIdx.x;
  __shared__ __align__(16) float kh[CHUNK][DHH];
  __shared__ __align__(16) float vl[CHUNK][DHH];
  int s = tid >> 3, d0 = (tid & 7) * 8;
  float p = (float)(CHUNK - 1 - s);
  long base = (long)(c * CHUNK + s) * DIM + h * DHH + d0;
  bf16x8 k8 = *(const bf16x8*)&kmat[base];
  bf16x8 v8 = *(const bf16x8*)&vmat[base];
#pragma unroll
  for (int j = 0; j < 8; j++) {
    float e2 = expf(decay_l[h * DHH + d0 + j]) * 1.4426950408889634f;
    kh[s][d0 + j] = (float)k8[j] * exp2f(-p * e2);
    vl[s][d0 + j] = (float)v8[j];
  }
  __syncthreads();
  int d = tid >> 2, e0 = (tid & 3) * 16;
  float acc[16];
#pragma unroll
  for (int j = 0; j < 16; j++) acc[j] = 0.f;
  for (int ss = 0; ss < CHUNK; ss++) {
    float kc = kh[ss][d];
#pragma unroll
    for (int j = 0; j < 16; j += 4) {
      float4 vv = *(const float4*)&vl[ss][e0 + j];
      acc[j] = fmaf(kc, vv.x, acc[j]);
      acc[j + 1] = fmaf(kc, vv.y, acc[j + 1]);
      acc[j + 2] = fmaf(kc, vv.z, acc[j + 2]);
      acc[j + 3] = fmaf(kc, vv.w, acc[j + 3]);
    }
  }
  float* out = &dS[(((long)c * NH + h) * DHH + d) * DHH + e0];
#pragma unroll
  for (int j = 0; j < 16; j += 4) {
    float4 o = {acc[j], acc[j + 1], acc[j + 2], acc[j + 3]};
    *(float4*)&out[j] = o;
  }
}

// ---------------- WKV phase B: sequential chunk-level scan (in place) ----------------
__global__ __launch_bounds__(256) void k_wkvb(float* __restrict__ dS,
                                              const float* __restrict__ decay_l) {
  int id = blockIdx.x * 256 + threadIdx.x;  // < NH*DHH*DHH
  int h = id >> 12, d = (id >> 6) & 63;
  float e2 = expf(decay_l[h * DHH + d]);
  float wc = expf(-(float)CHUNK * e2);
  float S = 0.f;
  for (int c = 0; c < NCH; c++) {
    float* p = &dS[(long)c * (NH * DHH * DHH) + id];
    float v = *p;
    *p = S;           // state at chunk start
    S = wc * S + v;   // advance
  }
}

// ---------------- WKV phase C: in-chunk replay + groupnorm + gate ----------------
#define WKV_STEP(dd, rc, kc, uc, oa)          \
  {                                           \
    float kv_ = (kc)*ve;                      \
    float tmp_ = fmaf((uc), ve, S[dd]);       \
    oa = fmaf((rc), tmp_, oa);                \
    S[dd] = fmaf(w[dd], S[dd], kv_);          \
  }

__global__ __launch_bounds__(64, 1) void k_wkvc(const bf16* __restrict__ rmat,
                                                const bf16* __restrict__ kmat,
                                                const bf16* __restrict__ vmat,
                                                const bf16* __restrict__ gmat,
                                                const float* __restrict__ decay_l,
                                                const float* __restrict__ faaaa_l,
                                                const float* __restrict__ lnxw,
                                                const float* __restrict__ lnxb,
                                                const float* __restrict__ Sc,
                                                bf16* __restrict__ y) {
  int c = blockIdx.x, h = blockIdx.y, lane = threadIdx.x;
  __shared__ __align__(16) float rl[CHUNK][DHH];
  __shared__ __align__(16) float kl[CHUNK][DHH];
  __shared__ __align__(16) float ukl[CHUNK][DHH];
  __shared__ __align__(16) float vls[CHUNK][DHH];
  __shared__ __align__(16) float wl[DHH];
  float u = faaaa_l[h * DHH + lane];
  wl[lane] = expf(-expf(decay_l[h * DHH + lane]));
  for (int i = 0; i < CHUNK; i++) {
    long base = (long)(c * CHUNK + i) * DIM + h * DHH + lane;
    float rv = (float)rmat[base], kv = (float)kmat[base], vv = (float)vmat[base];
    rl[i][lane] = rv;
    kl[i][lane] = kv;
    ukl[i][lane] = u * kv;
    vls[i][lane] = vv;
  }
  __syncthreads();
  float w[64], S[64];
#pragma unroll
  for (int q = 0; q < 16; q++) {
    float4 t4 = *(const float4*)&wl[q * 4];
    w[q * 4] = t4.x;
    w[q * 4 + 1] = t4.y;
    w[q * 4 + 2] = t4.z;
    w[q * 4 + 3] = t4.w;
  }
  const float* Sp = &Sc[((long)c * NH + h) * DHH * DHH + lane];
#pragma unroll
  for (int d = 0; d < 64; d++) S[d] = Sp[(long)d * DHH];
  float lw = lnxw[h * DHH + lane], lb = lnxb[h * DHH + lane];
#pragma unroll 1
  for (int t = 0; t < CHUNK; t++) {
    float ve = vls[t][lane];
    float o0 = 0.f, o1 = 0.f;
#pragma unroll
    for (int q = 0; q < 16; q++) {
      float4 r4 = *(const float4*)&rl[t][q * 4];
      float4 k4 = *(const float4*)&kl[t][q * 4];
      float4 u4 = *(const float4*)&ukl[t][q * 4];
      WKV_STEP(q * 4 + 0, r4.x, k4.x, u4.x, o0);
      WKV_STEP(q * 4 + 1, r4.y, k4.y, u4.y, o1);
      WKV_STEP(q * 4 + 2, r4.z, k4.z, u4.z, o0);
      WKV_STEP(q * 4 + 3, r4.w, k4.w, u4.w, o1);
    }
    float o = o0 + o1;
    float s1 = o, s2 = o * o;
#pragma unroll
    for (int off = 32; off >= 1; off >>= 1) {
      s1 += __shfl_xor(s1, off, 64);
      s2 += __shfl_xor(s2, off, 64);
    }
    float m = s1 * (1.f / 64.f), var = s2 * (1.f / 64.f) - m * m;
    float gn = (o - m) * rsqrtf(var + 1e-5f) * lw + lb;
    long gi = (long)(c * CHUNK + t) * DIM + h * DHH + lane;
    float gv = (float)gmat[gi];  // silu already applied by GEMM epilogue
    y[gi] = (bf16)(gn * gv);
  }
}

// ---------------- final LN + classifier on last token ----------------
__global__ __launch_bounds__(256) void k_final(const float* __restrict__ x,
                                               const float* __restrict__ w,
                                               const float* __restrict__ b,
                                               const float* __restrict__ sw,
                                               float* __restrict__ out) {
  int tid = threadIdx.x, c = tid * 4;
  float4 xc = *(const float4*)&x[(long)(T_SEQ - 1) * DIM + c];
  float s = xc.x + xc.y + xc.z + xc.w;
  float q = xc.x * xc.x + xc.y * xc.y + xc.z * xc.z + xc.w * xc.w;
  float d2 = 0.f, d3 = 0.f;
  block_reduce_4(s, q, d2, d3);
  float m = s * (1.f / DIM), var = q * (1.f / DIM) - m * m;
  float rs = rsqrtf(var + 1e-5f);
  float xs[4] = {xc.x, xc.y, xc.z, xc.w};
  float p0 = 0.f, p1 = 0.f;
#pragma unroll
  for (int j = 0; j < 4; j++) {
    float xn = (xs[j] - m) * rs * w[c + j] + b[c + j];
    p0 += xn * sw[c + j];
    p1 += xn * sw[DIM + c + j];
  }
  float e0 = 0.f, e1 = 0.f;
  block_reduce_4(p0, p1, e0, e1);
  if (tid == 0) {
    out[0] = p0;
    out[1] = p1;
  }
}

// ---------------- launcher ----------------
extern "C" void kernel_launch(void* const* d_in, const int* in_sizes, int n_in,
                              void* d_out, int out_size, void* d_ws, size_t ws_size,
                              hipStream_t stream) {
  (void)in_sizes; (void)n_in; (void)out_size; (void)ws_size;
  const int* idx = (const int*)d_in[0];
  const float* emb = (const float*)d_in[1];
  const float* ln0w = (const float*)d_in[2];
  const float* ln0b = (const float*)d_in[3];
  const float* ln1w = (const float*)d_in[4];
  const float* ln1b = (const float*)d_in[5];
  const float* mixr = (const float*)d_in[6];
  const float* mixk = (const float*)d_in[7];
  const float* mixv = (const float*)d_in[8];
  const float* mixg = (const float*)d_in[9];
  const float* decay = (const float*)d_in[10];
  const float* faaaa = (const float*)d_in[11];
  const float* Wr = (const float*)d_in[12];
  const float* Wk = (const float*)d_in[13];
  const float* Wv = (const float*)d_in[14];
  const float* Wg = (const float*)d_in[15];
  const float* Wo = (const float*)d_in[16];
  const float* lnxw = (const float*)d_in[17];
  const float* lnxb = (const float*)d_in[18];
  const float* ln2w = (const float*)d_in[19];
  const float* ln2b = (const float*)d_in[20];
  const float* cmixk = (const float*)d_in[21];
  const float* cmixr = (const float*)d_in[22];
  const float* cWk = (const float*)d_in[23];
  const float* cWv = (const float*)d_in[24];
  const float* cWr = (const float*)d_in[25];
  const float* lnoutw = (const float*)d_in[26];
  const float* lnoutb = (const float*)d_in[27];
  const float* scorew = (const float*)d_in[28];

  uint8_t* w8 = (uint8_t*)d_ws;
  float* xbuf = (float*)(w8 + 0);            //  8 MB fp32 T*D
  bf16* mix4 = (bf16*)(w8 + 8388608);        // 16 MB: xr|xk|xv|xg (bf16 T*D each)
  bf16* rkvg = (bf16*)(w8 + 25165824);       // 16 MB: r|k|v|g
  bf16* ybuf = (bf16*)(w8 + 41943040);       //  4 MB
  float* rrbuf = (float*)(w8 + 46137344);    //  8 MB
  bf16* kkbuf = (bf16*)(w8 + 54525952);      // 14 MB (T*F)
  float* dS = (float*)(w8 + 69206016);       // 16 MB (NCH*NH*DH*DH)
  bf16* Wt = (bf16*)(w8 + 85983232);         // 26 MB transposed layer weights

  const long TD = (long)T_SEQ * DIM;
  const long DD = (long)DIM * DIM;
  const long DF = (long)DIM * FF;

  bf16* WrT = Wt;              // r,k,v,g at stride DD
  bf16* WoT = Wt + 4 * DD;
  bf16* cWkT = Wt + 5 * DD;    // FF x DIM   (rows 0..FF-1)
  bf16* cWrT = cWkT + DF;      // DIM x DIM  (rows FF.., contiguous for MODE 5)
  bf16* cWvT = cWrT + DD;      // DIM x FF

  k_embed<<<T_SEQ, 256, 0, stream>>>(idx, emb, ln0w, ln0b, xbuf);

  for (int l = 0; l < NLAY; l++) {
    TrArgs ta;
    ta.src[0] = Wr + (long)l * DD;  ta.dst[0] = Wt + 0 * DD; ta.K[0] = DIM; ta.N[0] = DIM;
    ta.src[1] = Wk + (long)l * DD;  ta.dst[1] = Wt + 1 * DD; ta.K[1] = DIM; ta.N[1] = DIM;
    ta.src[2] = Wv + (long)l * DD;  ta.dst[2] = Wt + 2 * DD; ta.K[2] = DIM; ta.N[2] = DIM;
    ta.src[3] = Wg + (long)l * DD;  ta.dst[3] = Wt + 3 * DD; ta.K[3] = DIM; ta.N[3] = DIM;
    ta.src[4] = Wo + (long)l * DD;  ta.dst[4] = WoT;         ta.K[4] = DIM; ta.N[4] = DIM;
    ta.src[5] = cWk + (long)l * DF; ta.dst[5] = cWkT;        ta.K[5] = DIM; ta.N[5] = FF;
    ta.src[6] = cWr + (long)l * DD; ta.dst[6] = cWrT;        ta.K[6] = DIM; ta.N[6] = DIM;
    ta.src[7] = cWv + (long)l * DF; ta.dst[7] = cWvT;        ta.K[7] = FF;  ta.N[7] = DIM;
    // tiles: 5x256 (DxD) + 896 (cWk) + 256 (cWr) + 896 (cWv) = 3328
    const int ts[9] = {0, 256, 512, 768, 1024, 1280, 2176, 2432, 3328};
    for (int i = 0; i < 9; i++) ta.tstart[i] = ts[i];
    k_trans<<<3328, 256, 0, stream>>>(ta);

    k_lnmix<<<T_SEQ, 256, 0, stream>>>(xbuf, ln1w + l * DIM, ln1b + l * DIM,
                                       mixr + l * DIM, mixk + l * DIM,
                                       mixv + l * DIM, mixg + l * DIM, mix4, 4);

    // r|k|v|g: z=4 batch, 512 blocks (2/CU)
    k_gemm<0, 128, 1><<<dim3(8, 16, 4), 256, 0, stream>>>(mix4, WrT, (void*)rkvg, nullptr,
                                                          T_SEQ, DIM, DIM, TD, DD, TD);

    k_wkva<<<dim3(NCH, NH), 256, 0, stream>>>(rkvg + TD, rkvg + 2 * TD,
                                              decay + (long)l * NH * DHH, dS);
    k_wkvb<<<256, 256, 0, stream>>>(dS, decay + (long)l * NH * DHH);
    k_wkvc<<<dim3(NCH, NH), 64, 0, stream>>>(rkvg, rkvg + TD, rkvg + 2 * TD, rkvg + 3 * TD,
                                             decay + (long)l * NH * DHH,
                                             faaaa + (long)l * NH * DHH,
                                             lnxw + l * DIM, lnxb + l * DIM, dS, ybuf);

    // Wo residual: split-K x2 -> 512 blocks (2/CU), atomic f32 +=
    k_gemm<3, 64, 2><<<dim3(16, 16, 2), 256, 0, stream>>>(ybuf, WoT, (void*)xbuf, nullptr,
                                                          T_SEQ, DIM, DIM, 0, 0, 0);

    k_lnmix<<<T_SEQ, 256, 0, stream>>>(xbuf, ln2w + l * DIM, ln2b + l * DIM,
                                       cmixk + l * DIM, cmixr + l * DIM,
                                       nullptr, nullptr, mix4, 2);

    // fused cWk(relu^2, A=xk2)+cWr(sigmoid, A=xr2): N=4608 -> 576 blocks
    k_gemm<5, 128, 1><<<dim3(36, 16, 1), 256, 0, stream>>>(mix4, cWkT, (void*)kkbuf,
                                                           (const float*)rrbuf,
                                                           T_SEQ, FF, DIM, TD, 0, 0);

    // cWv: split-K x2 -> 512 blocks, atomic f32 += AUX*acc
    k_gemm<4, 64, 2><<<dim3(16, 16, 2), 256, 0, stream>>>(kkbuf, cWvT, (void*)xbuf, rrbuf,
                                                          T_SEQ, DIM, FF, 0, 0, 0);
  }

  k_final<<<1, 256, 0, stream>>>(xbuf, lnoutw, lnoutb, scorew, (float*)d_out);
}